// Round 8
// baseline (346.128 us; speedup 1.0000x reference)
//
#include <hip/hip_runtime.h>
#include <hip/hip_bf16.h>

// GraphPropLayer on MI355X — round 8: single fused front kernel
// (weight-prep + edge-binning + projection GEMM run concurrently), 8-deep
// gather pipeline in k_aggf, BK=64 node GEMM. 4 dispatches total.
// Pipeline:
//  (1) memset gcur
//  (2) k_front: [bins blocks | prep blocks | proj blocks] in one grid.
//      proj transposes W1/RW1 from global in-kernel (no Wt1 buffer).
//  (3) k_aggf: one block per 64-node bin: LDS counting-sort, per-key register
//      relu-accumulate, fp8 gathers 8-deep -> S_to/S_fr bf16 + deg.
//  (4) k_node: Hid = relu([S_to|S_fr|NS]@Wth^T + deg*u + bn1) in registers
//      -> LDS; out = Hid @ Wt2^T + bn2 + NS. Hid never hits global.

typedef __bf16 bf16;
typedef __attribute__((ext_vector_type(8))) __bf16 bf16x8;
typedef __attribute__((ext_vector_type(4))) __bf16 bf16x4v;
typedef __attribute__((ext_vector_type(4))) float floatx4;
typedef __attribute__((ext_vector_type(2))) float floatx2;

#define DD 128
#define HH 256
#define CAPB 1408      // records per 64-node bin; mean 1024, sigma 32 -> 12 sigma
#define MAXBINS 1600   // >= 2*NP/64

__device__ __forceinline__ bf16x8 ns8(const float* __restrict__ NS, int row, int col, int N) {
    bf16x8 v;
    if (row < N) {
        float4 f0 = *(const float4*)&NS[(size_t)row * DD + col];
        float4 f1 = *(const float4*)&NS[(size_t)row * DD + col + 4];
        v[0] = (bf16)f0.x; v[1] = (bf16)f0.y; v[2] = (bf16)f0.z; v[3] = (bf16)f0.w;
        v[4] = (bf16)f1.x; v[5] = (bf16)f1.y; v[6] = (bf16)f1.z; v[7] = (bf16)f1.w;
    } else {
        v = (bf16x8)(bf16)0.0f;
    }
    return v;
}

// ---------------- fused front: bins | prep | proj ----------------
__global__ __launch_bounds__(256) void k_front(
    const float* __restrict__ NS, const int* __restrict__ from_idx,
    const int* __restrict__ to_idx, const float* __restrict__ ef,
    const float* __restrict__ W1, const float* __restrict__ RW1,
    const float* __restrict__ W2, const float* __restrict__ RW2,
    const float* __restrict__ Wn1, const float* __restrict__ Wn2,
    const float* __restrict__ b2, const float* __restrict__ Rb2,
    int* __restrict__ gcur, int2* __restrict__ binbuf,
    unsigned char* __restrict__ Pn, bf16* __restrict__ Pf,
    bf16* __restrict__ Wth, bf16* __restrict__ Wt2,
    float* __restrict__ u, float* __restrict__ ru,
    int E, int N, int NP, int NBINS, int BINB, int MB) {
    __shared__ __align__(16) unsigned char smem[20608];
    const int b = blockIdx.x, t = threadIdx.x;

    if (b < BINB) {
        // ---------- edge binning: 2048 edges/block, 64-node bins ----------
        int* hist = (int*)smem;
        int* base = hist + MAXBINS;
        const int NBF = NP >> 6;
        for (int i = t; i < NBINS; i += 256) hist[i] = 0;
        __syncthreads();
        const int e0 = b * 2048;
        int f[8], tt[8]; float w[8]; bool valid[8];
#pragma unroll
        for (int q = 0; q < 8; ++q) {
            int e = e0 + q * 256 + t;
            valid[q] = e < E;
            int ec = valid[q] ? e : 0;
            f[q] = from_idx[ec]; tt[q] = to_idx[ec]; w[q] = ef[ec];
        }
#pragma unroll
        for (int q = 0; q < 8; ++q) {
            if (valid[q]) {
                atomicAdd(&hist[tt[q] >> 6], 1);
                atomicAdd(&hist[NBF + (f[q] >> 6)], 1);
            }
        }
        __syncthreads();
        for (int i = t; i < NBINS; i += 256) {
            int h = hist[i];
            base[i] = h ? atomicAdd(&gcur[i], h) : 0;
            hist[i] = 0;
        }
        __syncthreads();
#pragma unroll
        for (int q = 0; q < 8; ++q) {
            if (valid[q]) {
                int wb = __float_as_int(w[q]);
                int b1 = tt[q] >> 6;
                int r1 = base[b1] + atomicAdd(&hist[b1], 1);
                if (r1 < CAPB)
                    binbuf[(size_t)b1 * CAPB + r1] = make_int2(((tt[q] & 63) << 17) | f[q], wb);
                int b2i = NBF + (f[q] >> 6);
                int r2 = base[b2i] + atomicAdd(&hist[b2i], 1);
                if (r2 < CAPB)
                    binbuf[(size_t)b2i * CAPB + r2] = make_int2(((f[q] & 63) << 17) | tt[q], wb);
            }
        }
        return;
    }

    if (b < BINB + 769) {
        // ---------- weight prep (consumed only by k_node) ----------
        int bb = b - BINB;
        if (bb < 640) {                  // Wth[m][k]: W2@Wn1_top | RW2@Wn1_top | Wn1_bot
            int k = bb, m = t;
            float v;
            if (k < 512) {
                const float* Wsrc = (k < 256) ? W2 : RW2;
                int i = k & 255;
                float acc = 0.f;
                for (int j = 0; j < 256; ++j) acc += Wsrc[i * 256 + j] * Wn1[j * 256 + m];
                v = acc;
            } else {
                v = Wn1[(256 + k - 512) * 256 + m];
            }
            Wth[m * 640 + k] = (bf16)v;
        } else if (bb < 768) {           // Wt2[n][k] = Wn2^T
            int idx = (bb - 640) * 256 + t;
            int n = idx >> 8, k = idx & 255;
            Wt2[idx] = (bf16)Wn2[k * 128 + n];
        } else {                         // u = b2@Wn1_top, ru = Rb2@Wn1_top
            int m = t;
            float a = 0.f, c2 = 0.f;
            for (int j = 0; j < 256; ++j) {
                float w = Wn1[j * 256 + m];
                a += b2[j] * w;
                c2 += Rb2[j] * w;
            }
            u[m] = a;
            ru[m] = c2;
        }
        return;
    }

    // ---------- projection GEMM: P = NS(bf16) @ [W1|RW1 blocks]^T ----------
    {
        bf16 (*As)[64][40] = (bf16(*)[64][40])smem;              // [2][64][40]
        bf16 (*Bs)[64][40] = (bf16(*)[64][40])(smem + 10240);    // [2][64][40]
        const int p = b - (BINB + 769);
        const int col0 = (p / MB) * 64;           // col-major: same col clusters
        const int row0 = (p % MB) * 64;
        const int wv = t >> 6, lane = t & 63;
        const int l15 = lane & 15, quad = lane >> 4;
        const int srow = t >> 2, kc = (t & 3) * 8;
        // B source: transpose of W1/RW1 block
        const int cb = col0 >> 8;
        const float* Wsrc = (cb < 2) ? W1 : RW1;
        const int krow_off = (cb & 1) ? 128 : 0;
        const int nb = col0 & 255;
        const int nloc = t & 63, kq = t >> 6;     // kq: 16 k's per thread
        const int hB = kq >> 1, kk0 = (kq & 1) * 16;
        floatx4 acc[4] = {};
        for (int k0 = 0; k0 < DD; k0 += 64) {
            bf16x8 av0 = ns8(NS, row0 + srow, k0 + kc, N);
            bf16x8 av1 = ns8(NS, row0 + srow, k0 + 32 + kc, N);
            float bvals[16];
#pragma unroll
            for (int j = 0; j < 16; ++j)
                bvals[j] = Wsrc[(size_t)(krow_off + k0 + hB * 32 + kk0 + j) * 256 + nb + nloc];
            __syncthreads();
            *(bf16x8*)&As[0][srow][kc] = av0;
            *(bf16x8*)&As[1][srow][kc] = av1;
#pragma unroll
            for (int j = 0; j < 16; ++j)
                Bs[hB][nloc][kk0 + j] = (bf16)bvals[j];
            __syncthreads();
#pragma unroll
            for (int h = 0; h < 2; ++h) {
                bf16x8 bfr = *(const bf16x8*)&Bs[h][wv * 16 + l15][quad * 8];
#pragma unroll
                for (int r = 0; r < 4; ++r) {
                    bf16x8 afr = *(const bf16x8*)&As[h][r * 16 + l15][quad * 8];
                    acc[r] = __builtin_amdgcn_mfma_f32_16x16x32_bf16(afr, bfr, acc[r], 0, 0, 0);
                }
            }
        }
        const int ocol = col0 + wv * 16 + l15;        // [0,1024)
        const int ch = ocol & 255;
        const int half = (ocol >> 9) & 1;             // 0=fwd pair, 1=rev pair
        const bool isNbr = ((ocol >> 8) & 1) == 0;    // blocks 0,2 -> fp8 nbr halves
#pragma unroll
        for (int r = 0; r < 4; ++r)
#pragma unroll
            for (int i = 0; i < 4; ++i) {
                int orow = row0 + r * 16 + quad * 4 + i;
                float v = acc[r][i];
                if (isNbr) {
                    int pk = __builtin_amdgcn_cvt_pk_fp8_f32(v, v, 0, false);
                    Pn[(size_t)orow * 512 + half * 256 + ch] = (unsigned char)(pk & 0xFF);
                } else {
                    Pf[(size_t)orow * 512 + half * 256 + ch] = (bf16)v;
                }
            }
    }
}

// ---------------- aggregation: one block per 64-node bin, 8-deep gathers ----------------
__global__ __launch_bounds__(256) void k_aggf(
    const unsigned char* __restrict__ Pn, const bf16* __restrict__ Pf,
    const int2* __restrict__ binbuf, const int* __restrict__ gcnt,
    const float* __restrict__ W1, const float* __restrict__ b1,
    const float* __restrict__ RW1, const float* __restrict__ Rb1,
    bf16* __restrict__ S_to, bf16* __restrict__ S_fr,
    int* __restrict__ deg, int NP) {
    __shared__ int hist[64], kstart[64], cur[64], scanbuf[64];
    __shared__ int2 srec[CAPB];
    const int b = blockIdx.x, t = threadIdx.x;
    const int NBF = NP >> 6;
    const bool rev = b >= NBF;
    const int node0 = (rev ? b - NBF : b) << 6;
    int cnt = gcnt[b]; if (cnt > CAPB) cnt = CAPB;
    const int2* bin = binbuf + (size_t)b * CAPB;
    if (t < 64) hist[t] = 0;
    __syncthreads();
    for (int i = t; i < cnt; i += 256)
        atomicAdd(&hist[((unsigned)bin[i].x) >> 17], 1);
    __syncthreads();
    if (t < 64) scanbuf[t] = hist[t];
    __syncthreads();
    for (int d = 1; d < 64; d <<= 1) {
        int v = (t < 64 && t >= d) ? scanbuf[t - d] : 0;
        __syncthreads();
        if (t < 64) scanbuf[t] += v;
        __syncthreads();
    }
    if (t < 64) { kstart[t] = scanbuf[t] - hist[t]; cur[t] = scanbuf[t] - hist[t]; }
    __syncthreads();
    for (int i = t; i < cnt; i += 256) {
        int2 r = bin[i];
        int rk = atomicAdd(&cur[((unsigned)r.x) >> 17], 1);
        srec[rk] = r;
    }
    __syncthreads();
    const int wv = t >> 6, lane = t & 63, c = lane * 4;
    const int fixoff = rev ? 256 : 0;     // into Pf row (elements)
    const int nbroff = rev ? 256 : 0;     // into Pn row (bytes)
    const float* bb = rev ? Rb1 : b1;
    const float* wl = (rev ? RW1 : W1) + 65536;   // row 256 of [257,256]
    float4 bv = *(const float4*)&bb[c];
    float4 wv4 = *(const float4*)&wl[c];
    bf16* Sarr = rev ? S_fr : S_to;
    for (int key = wv; key < 64; key += 4) {
        int node = node0 + key;
        bf16x4v pf = *(const bf16x4v*)&Pf[(size_t)node * 512 + fixoff + c];
        float fx0 = (float)pf[0] + bv.x;
        float fx1 = (float)pf[1] + bv.y;
        float fx2 = (float)pf[2] + bv.z;
        float fx3 = (float)pf[3] + bv.w;
        int beg = kstart[key], kc2 = hist[key], end = beg + kc2;
        float a0 = 0.f, a1 = 0.f, a2 = 0.f, a3 = 0.f;
        int j = beg;
        for (; j + 8 <= end; j += 8) {
            int2 rr[8]; int qq[8];
#pragma unroll
            for (int z = 0; z < 8; ++z) rr[z] = srec[j + z];
#pragma unroll
            for (int z = 0; z < 8; ++z)
                qq[z] = *(const int*)&Pn[(size_t)(rr[z].x & 0x1FFFF) * 512 + nbroff + c];
#pragma unroll
            for (int z = 0; z < 8; ++z) {
                float w = __int_as_float(rr[z].y);
                floatx2 lo = __builtin_amdgcn_cvt_pk_f32_fp8(qq[z], false);
                floatx2 hi = __builtin_amdgcn_cvt_pk_f32_fp8(qq[z], true);
                a0 += fmaxf(fx0 + lo.x + w * wv4.x, 0.f);
                a1 += fmaxf(fx1 + lo.y + w * wv4.y, 0.f);
                a2 += fmaxf(fx2 + hi.x + w * wv4.z, 0.f);
                a3 += fmaxf(fx3 + hi.y + w * wv4.w, 0.f);
            }
        }
        for (; j < end; ++j) {
            int2 r = srec[j];
            int qq = *(const int*)&Pn[(size_t)(r.x & 0x1FFFF) * 512 + nbroff + c];
            float w = __int_as_float(r.y);
            floatx2 lo = __builtin_amdgcn_cvt_pk_f32_fp8(qq, false);
            floatx2 hi = __builtin_amdgcn_cvt_pk_f32_fp8(qq, true);
            a0 += fmaxf(fx0 + lo.x + w * wv4.x, 0.f);
            a1 += fmaxf(fx1 + lo.y + w * wv4.y, 0.f);
            a2 += fmaxf(fx2 + hi.x + w * wv4.z, 0.f);
            a3 += fmaxf(fx3 + hi.y + w * wv4.w, 0.f);
        }
        bf16x4v o;
        o[0] = (bf16)a0; o[1] = (bf16)a1; o[2] = (bf16)a2; o[3] = (bf16)a3;
        *(bf16x4v*)&Sarr[(size_t)node * 256 + c] = o;
        if (lane == 0) deg[(rev ? NP : 0) + node] = kc2;
    }
}

// ---------------- fused node MLP: Hid in LDS, out = Hid@Wt2^T + bn2 + NS ----------------
__global__ __launch_bounds__(256) void k_node(
    const bf16* __restrict__ S_to, const bf16* __restrict__ S_fr,
    const float* __restrict__ NS, const bf16* __restrict__ Wth,
    const bf16* __restrict__ Wt2,
    const float* __restrict__ u, const float* __restrict__ ru,
    const float* __restrict__ bn1, const float* __restrict__ bn2,
    const int* __restrict__ deg, float* __restrict__ out, int NP, int N) {
    __shared__ __align__(16) unsigned char smem[51200];   // As(10240)+Bs(40960); Hs(33792) aliases
    bf16 (*As)[64][40]  = (bf16(*)[64][40])smem;          // [2][64][40]
    bf16 (*Bs)[256][40] = (bf16(*)[256][40])(smem + 10240); // [2][256][40]
    bf16 (*Hs)[264] = (bf16(*)[264])smem;                 // [64][264]
    const int tid = threadIdx.x;
    const int wv = tid >> 6, lane = tid & 63;
    const int l15 = lane & 15, quad = lane >> 4;
    const int row0 = blockIdx.x * 64;
    const int srow4 = tid >> 2, kc = (tid & 3) * 8;
    floatx4 acc[4][4] = {};   // [colstrip][rowtile]; wave covers cols wv*64..+64
    const int arow = row0 + srow4;
    auto loadA = [&](int k) -> bf16x8 {
        if (k < 512) {
            const bf16* S = (k < 256) ? S_to : S_fr;
            return *(const bf16x8*)&S[(size_t)arow * 256 + (k & 255) + kc];
        }
        return ns8(NS, arow, (k - 512) + kc, N);
    };
    for (int k0 = 0; k0 < 640; k0 += 64) {
        bf16x8 av0 = loadA(k0);
        bf16x8 av1 = loadA(k0 + 32);
        bf16x8 bv[2][4];
#pragma unroll
        for (int h = 0; h < 2; ++h)
#pragma unroll
            for (int j = 0; j < 4; ++j)
                bv[h][j] = *(const bf16x8*)&Wth[(size_t)(srow4 + 64 * j) * 640 + k0 + h * 32 + kc];
        __syncthreads();
        *(bf16x8*)&As[0][srow4][kc] = av0;
        *(bf16x8*)&As[1][srow4][kc] = av1;
#pragma unroll
        for (int h = 0; h < 2; ++h)
#pragma unroll
            for (int j = 0; j < 4; ++j)
                *(bf16x8*)&Bs[h][srow4 + 64 * j][kc] = bv[h][j];
        __syncthreads();
#pragma unroll
        for (int h = 0; h < 2; ++h)
#pragma unroll
            for (int s = 0; s < 4; ++s) {
                bf16x8 bfr = *(const bf16x8*)&Bs[h][wv * 64 + s * 16 + l15][quad * 8];
#pragma unroll
                for (int r = 0; r < 4; ++r) {
                    bf16x8 afr = *(const bf16x8*)&As[h][r * 16 + l15][quad * 8];
                    acc[s][r] = __builtin_amdgcn_mfma_f32_16x16x32_bf16(afr, bfr, acc[s][r], 0, 0, 0);
                }
            }
    }
    __syncthreads();   // all As/Bs reads done before Hs overwrite
    // epilogue 1: deg terms + bias + relu -> Hs
#pragma unroll
    for (int s = 0; s < 4; ++s) {
        int col = wv * 64 + s * 16 + l15;
        float uc = u[col], rc = ru[col], bc = bn1[col];
#pragma unroll
        for (int r = 0; r < 4; ++r)
#pragma unroll
            for (int i = 0; i < 4; ++i) {
                int row = r * 16 + quad * 4 + i;
                float v = acc[s][r][i] + (float)deg[row0 + row] * uc
                        + (float)deg[NP + row0 + row] * rc + bc;
                Hs[row][col] = (bf16)fmaxf(v, 0.f);
            }
    }
    __syncthreads();
    // phase 2: out[64x128]; wave covers cols wv*32..+32 (2 strips)
    floatx4 acc2[2][4] = {};
    for (int k0 = 0; k0 < HH; k0 += 32) {
        bf16x8 afr[4];
#pragma unroll
        for (int r = 0; r < 4; ++r)
            afr[r] = *(const bf16x8*)&Hs[r * 16 + l15][k0 + quad * 8];
#pragma unroll
        for (int s = 0; s < 2; ++s) {
            int col = wv * 32 + s * 16 + l15;
            bf16x8 bfr = *(const bf16x8*)&Wt2[(size_t)col * HH + k0 + quad * 8];
#pragma unroll
            for (int r = 0; r < 4; ++r)
                acc2[s][r] = __builtin_amdgcn_mfma_f32_16x16x32_bf16(afr[r], bfr, acc2[s][r], 0, 0, 0);
        }
    }
#pragma unroll
    for (int s = 0; s < 2; ++s) {
        int ocol = wv * 32 + s * 16 + l15;
        float bb = bn2[ocol];
#pragma unroll
        for (int r = 0; r < 4; ++r)
#pragma unroll
            for (int i = 0; i < 4; ++i) {
                int orow = row0 + r * 16 + quad * 4 + i;
                if (orow < N)
                    out[(size_t)orow * DD + ocol] = acc2[s][r][i] + bb + NS[(size_t)orow * DD + ocol];
            }
    }
}

extern "C" void kernel_launch(void* const* d_in, const int* in_sizes, int n_in,
                              void* d_out, int out_size, void* d_ws, size_t ws_size,
                              hipStream_t stream) {
    const float* NS   = (const float*)d_in[0];
    const float* ef   = (const float*)d_in[1];
    const int* from_idx = (const int*)d_in[2];
    const int* to_idx   = (const int*)d_in[3];
    const float* W1  = (const float*)d_in[4];
    const float* b1  = (const float*)d_in[5];
    const float* W2  = (const float*)d_in[6];
    const float* b2  = (const float*)d_in[7];
    const float* RW1 = (const float*)d_in[8];
    const float* Rb1 = (const float*)d_in[9];
    const float* RW2 = (const float*)d_in[10];
    const float* Rb2 = (const float*)d_in[11];
    const float* Wn1 = (const float*)d_in[12];
    const float* bn1 = (const float*)d_in[13];
    const float* Wn2 = (const float*)d_in[14];
    const float* bn2 = (const float*)d_in[15];

    const int N  = in_sizes[0] / DD;
    const int E  = in_sizes[2];
    const int NP = ((N + 63) / 64) * 64;
    const int MB = NP / 64;
    const int NBF = NP / 64;
    const int NBINS = 2 * NBF;
    const int BINB = (E + 2047) / 2048;
    const int FRONT = BINB + 769 + 16 * MB;

    char* base = (char*)d_ws;
    size_t off_b = 0;
    auto alloc = [&](size_t b) { size_t o = off_b; off_b += (b + 255) & ~(size_t)255; return o; };
    unsigned char* Pn = (unsigned char*)(base + alloc((size_t)NP * 512));
    bf16* Pf   = (bf16*)(base + alloc((size_t)NP * 512 * 2));
    bf16* S_to = (bf16*)(base + alloc((size_t)NP * 256 * 2));
    bf16* S_fr = (bf16*)(base + alloc((size_t)NP * 256 * 2));
    int* deg   = (int*)(base + alloc((size_t)2 * NP * 4));
    int* gcur  = (int*)(base + alloc((size_t)NBINS * 4));
    int2* binbuf = (int2*)(base + alloc((size_t)NBINS * CAPB * 8));
    bf16* Wth = (bf16*)(base + alloc(256 * 640 * 2));
    bf16* Wt2 = (bf16*)(base + alloc(128 * 256 * 2));
    float* u  = (float*)(base + alloc(256 * 4));
    float* ru = (float*)(base + alloc(256 * 4));

    hipMemsetAsync(gcur, 0, (size_t)NBINS * 4, stream);

    k_front<<<FRONT, 256, 0, stream>>>(NS, from_idx, to_idx, ef,
                                       W1, RW1, W2, RW2, Wn1, Wn2, b2, Rb2,
                                       gcur, binbuf, Pn, Pf, Wth, Wt2, u, ru,
                                       E, N, NP, NBINS, BINB, MB);
    k_aggf<<<NBINS, 256, 0, stream>>>(Pn, Pf, binbuf, gcur, W1, b1, RW1, Rb1,
                                      S_to, S_fr, deg, NP);
    k_node<<<MB, 256, 0, stream>>>(S_to, S_fr, NS, Wth, Wt2, u, ru, bn1, bn2,
                                   deg, (float*)d_out, NP, N);
}

// Round 9
// 329.390 us; speedup vs baseline: 1.0508x; 1.0508x over previous
//
#include <hip/hip_runtime.h>
#include <hip/hip_bf16.h>

// GraphPropLayer on MI355X — round 9: conflict-free proj staging (Wt1 buffer
// restored), L2-friendly proj block order, 32-node bins in aggregation.
// 4 dispatches:
//  (1) k_pre: Wt1 transpose prep + gcur zeroing.
//  (2) k_front: [bins | Wth/Wt2/u/ru prep | proj GEMM] in one grid.
//  (3) k_aggf: one block per 32-node bin: LDS counting-sort, register
//      relu-accumulate, 8-deep fp8 gathers -> S_to/S_fr + deg.
//  (4) k_node: Hid = relu([S|S|NS]@Wth^T + deg*u + bn1) in regs -> LDS;
//      out = Hid @ Wt2^T + bn2 + NS. Hid never hits global.

typedef __bf16 bf16;
typedef __attribute__((ext_vector_type(8))) __bf16 bf16x8;
typedef __attribute__((ext_vector_type(4))) __bf16 bf16x4v;
typedef __attribute__((ext_vector_type(4))) float floatx4;
typedef __attribute__((ext_vector_type(2))) float floatx2;

#define DD 128
#define HH 256
#define CAPB 800       // records per 32-node bin; mean 512, sigma 23 -> 12 sigma
#define MAXBINS 3200   // >= 2*NP/32 for N <= 51200

__device__ __forceinline__ bf16x8 ns8(const float* __restrict__ NS, int row, int col, int N) {
    bf16x8 v;
    if (row < N) {
        float4 f0 = *(const float4*)&NS[(size_t)row * DD + col];
        float4 f1 = *(const float4*)&NS[(size_t)row * DD + col + 4];
        v[0] = (bf16)f0.x; v[1] = (bf16)f0.y; v[2] = (bf16)f0.z; v[3] = (bf16)f0.w;
        v[4] = (bf16)f1.x; v[5] = (bf16)f1.y; v[6] = (bf16)f1.z; v[7] = (bf16)f1.w;
    } else {
        v = (bf16x8)(bf16)0.0f;
    }
    return v;
}

// ---------------- pre: Wt1 transpose + gcur zero ----------------
__global__ void k_pre(const float* __restrict__ W1, const float* __restrict__ RW1,
                      bf16* __restrict__ Wt1, int* __restrict__ gcur, int NBINS) {
    const int b = blockIdx.x, t = threadIdx.x;
    if (b < 512) {                       // Wt1[n][k]: transposed W1/RW1 blocks
        int idx = b * 256 + t;
        int n = idx >> 7, k = idx & 127;
        float v;
        if (n < 256)      v = W1[k * 256 + n];
        else if (n < 512) v = W1[(128 + k) * 256 + (n - 256)];
        else if (n < 768) v = RW1[k * 256 + (n - 512)];
        else              v = RW1[(128 + k) * 256 + (n - 768)];
        Wt1[idx] = (bf16)v;
    } else {
        int i = (b - 512) * 256 + t;
        if (i < NBINS) gcur[i] = 0;
    }
}

// ---------------- fused front: bins | prep | proj ----------------
__global__ __launch_bounds__(256) void k_front(
    const float* __restrict__ NS, const int* __restrict__ from_idx,
    const int* __restrict__ to_idx, const float* __restrict__ ef,
    const float* __restrict__ W2, const float* __restrict__ RW2,
    const float* __restrict__ Wn1, const float* __restrict__ Wn2,
    const float* __restrict__ b2, const float* __restrict__ Rb2,
    const bf16* __restrict__ Wt1,
    int* __restrict__ gcur, int2* __restrict__ binbuf,
    unsigned char* __restrict__ Pn, bf16* __restrict__ Pf,
    bf16* __restrict__ Wth, bf16* __restrict__ Wt2,
    float* __restrict__ u, float* __restrict__ ru,
    int E, int N, int NP, int NBINS, int BINB, int MB) {
    __shared__ __align__(16) unsigned char smem[25600];
    const int b = blockIdx.x, t = threadIdx.x;

    if (b < BINB) {
        // ---------- edge binning: 2048 edges/block, 32-node bins ----------
        int* hist = (int*)smem;
        int* base = hist + MAXBINS;
        const int NBF = NP >> 5;
        for (int i = t; i < NBINS; i += 256) hist[i] = 0;
        __syncthreads();
        const int e0 = b * 2048;
        int f[8], tt[8]; float w[8]; bool valid[8];
#pragma unroll
        for (int q = 0; q < 8; ++q) {
            int e = e0 + q * 256 + t;
            valid[q] = e < E;
            int ec = valid[q] ? e : 0;
            f[q] = from_idx[ec]; tt[q] = to_idx[ec]; w[q] = ef[ec];
        }
#pragma unroll
        for (int q = 0; q < 8; ++q) {
            if (valid[q]) {
                atomicAdd(&hist[tt[q] >> 5], 1);
                atomicAdd(&hist[NBF + (f[q] >> 5)], 1);
            }
        }
        __syncthreads();
        for (int i = t; i < NBINS; i += 256) {
            int h = hist[i];
            base[i] = h ? atomicAdd(&gcur[i], h) : 0;
            hist[i] = 0;
        }
        __syncthreads();
#pragma unroll
        for (int q = 0; q < 8; ++q) {
            if (valid[q]) {
                int wb = __float_as_int(w[q]);
                int b1 = tt[q] >> 5;
                int r1 = base[b1] + atomicAdd(&hist[b1], 1);
                if (r1 < CAPB)
                    binbuf[(size_t)b1 * CAPB + r1] = make_int2(((tt[q] & 31) << 17) | f[q], wb);
                int b2i = NBF + (f[q] >> 5);
                int r2 = base[b2i] + atomicAdd(&hist[b2i], 1);
                if (r2 < CAPB)
                    binbuf[(size_t)b2i * CAPB + r2] = make_int2(((f[q] & 31) << 17) | tt[q], wb);
            }
        }
        return;
    }

    if (b < BINB + 769) {
        // ---------- weight prep (consumed only by k_node) ----------
        int bb = b - BINB;
        if (bb < 640) {                  // Wth[m][k]: W2@Wn1_top | RW2@Wn1_top | Wn1_bot
            int k = bb, m = t;
            float v;
            if (k < 512) {
                const float* Wsrc = (k < 256) ? W2 : RW2;
                int i = k & 255;
                float acc = 0.f;
                for (int j = 0; j < 256; ++j) acc += Wsrc[i * 256 + j] * Wn1[j * 256 + m];
                v = acc;
            } else {
                v = Wn1[(256 + k - 512) * 256 + m];
            }
            Wth[m * 640 + k] = (bf16)v;
        } else if (bb < 768) {           // Wt2[n][k] = Wn2^T
            int idx = (bb - 640) * 256 + t;
            int n = idx >> 8, k = idx & 255;
            Wt2[idx] = (bf16)Wn2[k * 128 + n];
        } else {                         // u = b2@Wn1_top, ru = Rb2@Wn1_top
            int m = t;
            float a = 0.f, c2 = 0.f;
            for (int j = 0; j < 256; ++j) {
                float w = Wn1[j * 256 + m];
                a += b2[j] * w;
                c2 += Rb2[j] * w;
            }
            u[m] = a;
            ru[m] = c2;
        }
        return;
    }

    // ---------- projection GEMM: P = NS(bf16) @ Wt1^T ----------
    {
        bf16 (*As)[64][40] = (bf16(*)[64][40])smem;              // [2][64][40]
        bf16 (*Bs)[64][40] = (bf16(*)[64][40])(smem + 10240);    // [2][64][40]
        const int p = b - (BINB + 769);
        const int row0 = (p >> 4) * 64;           // 16 consecutive blocks share NS rows
        const int col0 = (p & 15) * 64;
        const int wv = t >> 6, lane = t & 63;
        const int l15 = lane & 15, quad = lane >> 4;
        const int srow = t >> 2, kc = (t & 3) * 8;
        floatx4 acc[4] = {};
        for (int k0 = 0; k0 < DD; k0 += 64) {
            bf16x8 av0 = ns8(NS, row0 + srow, k0 + kc, N);
            bf16x8 av1 = ns8(NS, row0 + srow, k0 + 32 + kc, N);
            bf16x8 bv0 = *(const bf16x8*)&Wt1[(size_t)(col0 + srow) * DD + k0 + kc];
            bf16x8 bv1 = *(const bf16x8*)&Wt1[(size_t)(col0 + srow) * DD + k0 + 32 + kc];
            __syncthreads();
            *(bf16x8*)&As[0][srow][kc] = av0;
            *(bf16x8*)&As[1][srow][kc] = av1;
            *(bf16x8*)&Bs[0][srow][kc] = bv0;
            *(bf16x8*)&Bs[1][srow][kc] = bv1;
            __syncthreads();
#pragma unroll
            for (int h = 0; h < 2; ++h) {
                bf16x8 bfr = *(const bf16x8*)&Bs[h][wv * 16 + l15][quad * 8];
#pragma unroll
                for (int r = 0; r < 4; ++r) {
                    bf16x8 afr = *(const bf16x8*)&As[h][r * 16 + l15][quad * 8];
                    acc[r] = __builtin_amdgcn_mfma_f32_16x16x32_bf16(afr, bfr, acc[r], 0, 0, 0);
                }
            }
        }
        const int ocol = col0 + wv * 16 + l15;        // [0,1024)
        const int ch = ocol & 255;
        const int half = (ocol >> 9) & 1;             // 0=fwd pair, 1=rev pair
        const bool isNbr = ((ocol >> 8) & 1) == 0;    // blocks 0,2 -> fp8 nbr halves
#pragma unroll
        for (int r = 0; r < 4; ++r)
#pragma unroll
            for (int i = 0; i < 4; ++i) {
                int orow = row0 + r * 16 + quad * 4 + i;
                float v = acc[r][i];
                if (isNbr) {
                    int pk = __builtin_amdgcn_cvt_pk_fp8_f32(v, v, 0, false);
                    Pn[(size_t)orow * 512 + half * 256 + ch] = (unsigned char)(pk & 0xFF);
                } else {
                    Pf[(size_t)orow * 512 + half * 256 + ch] = (bf16)v;
                }
            }
    }
}

// ---------------- aggregation: one block per 32-node bin, 8-deep gathers ----------------
__global__ __launch_bounds__(256) void k_aggf(
    const unsigned char* __restrict__ Pn, const bf16* __restrict__ Pf,
    const int2* __restrict__ binbuf, const int* __restrict__ gcnt,
    const float* __restrict__ W1, const float* __restrict__ b1,
    const float* __restrict__ RW1, const float* __restrict__ Rb1,
    bf16* __restrict__ S_to, bf16* __restrict__ S_fr,
    int* __restrict__ deg, int NP) {
    __shared__ int hist[32], kstart[32], cur[32], scanbuf[32];
    __shared__ int2 srec[CAPB];
    const int b = blockIdx.x, t = threadIdx.x;
    const int NBF = NP >> 5;
    const bool rev = b >= NBF;
    const int node0 = (rev ? b - NBF : b) << 5;
    int cnt = gcnt[b]; if (cnt > CAPB) cnt = CAPB;
    const int2* bin = binbuf + (size_t)b * CAPB;
    if (t < 32) hist[t] = 0;
    __syncthreads();
    for (int i = t; i < cnt; i += 256)
        atomicAdd(&hist[((unsigned)bin[i].x) >> 17], 1);
    __syncthreads();
    if (t < 32) scanbuf[t] = hist[t];
    __syncthreads();
    for (int d = 1; d < 32; d <<= 1) {
        int v = (t < 32 && t >= d) ? scanbuf[t - d] : 0;
        __syncthreads();
        if (t < 32) scanbuf[t] += v;
        __syncthreads();
    }
    if (t < 32) { kstart[t] = scanbuf[t] - hist[t]; cur[t] = scanbuf[t] - hist[t]; }
    __syncthreads();
    for (int i = t; i < cnt; i += 256) {
        int2 r = bin[i];
        int rk = atomicAdd(&cur[((unsigned)r.x) >> 17], 1);
        srec[rk] = r;
    }
    __syncthreads();
    const int wv = t >> 6, lane = t & 63, c = lane * 4;
    const int fixoff = rev ? 256 : 0;     // into Pf row (elements)
    const int nbroff = rev ? 256 : 0;     // into Pn row (bytes)
    const float* bb = rev ? Rb1 : b1;
    const float* wl = (rev ? RW1 : W1) + 65536;   // row 256 of [257,256]
    float4 bv = *(const float4*)&bb[c];
    float4 wv4 = *(const float4*)&wl[c];
    bf16* Sarr = rev ? S_fr : S_to;
    for (int key = wv; key < 32; key += 4) {
        int node = node0 + key;
        bf16x4v pf = *(const bf16x4v*)&Pf[(size_t)node * 512 + fixoff + c];
        float fx0 = (float)pf[0] + bv.x;
        float fx1 = (float)pf[1] + bv.y;
        float fx2 = (float)pf[2] + bv.z;
        float fx3 = (float)pf[3] + bv.w;
        int beg = kstart[key], kc2 = hist[key], end = beg + kc2;
        float a0 = 0.f, a1 = 0.f, a2 = 0.f, a3 = 0.f;
        int j = beg;
        for (; j + 8 <= end; j += 8) {
            int2 rr[8]; int qq[8];
#pragma unroll
            for (int z = 0; z < 8; ++z) rr[z] = srec[j + z];
#pragma unroll
            for (int z = 0; z < 8; ++z)
                qq[z] = *(const int*)&Pn[(size_t)(rr[z].x & 0x1FFFF) * 512 + nbroff + c];
#pragma unroll
            for (int z = 0; z < 8; ++z) {
                float w = __int_as_float(rr[z].y);
                floatx2 lo = __builtin_amdgcn_cvt_pk_f32_fp8(qq[z], false);
                floatx2 hi = __builtin_amdgcn_cvt_pk_f32_fp8(qq[z], true);
                a0 += fmaxf(fx0 + lo.x + w * wv4.x, 0.f);
                a1 += fmaxf(fx1 + lo.y + w * wv4.y, 0.f);
                a2 += fmaxf(fx2 + hi.x + w * wv4.z, 0.f);
                a3 += fmaxf(fx3 + hi.y + w * wv4.w, 0.f);
            }
        }
        for (; j < end; ++j) {
            int2 r = srec[j];
            int qq = *(const int*)&Pn[(size_t)(r.x & 0x1FFFF) * 512 + nbroff + c];
            float w = __int_as_float(r.y);
            floatx2 lo = __builtin_amdgcn_cvt_pk_f32_fp8(qq, false);
            floatx2 hi = __builtin_amdgcn_cvt_pk_f32_fp8(qq, true);
            a0 += fmaxf(fx0 + lo.x + w * wv4.x, 0.f);
            a1 += fmaxf(fx1 + lo.y + w * wv4.y, 0.f);
            a2 += fmaxf(fx2 + hi.x + w * wv4.z, 0.f);
            a3 += fmaxf(fx3 + hi.y + w * wv4.w, 0.f);
        }
        bf16x4v o;
        o[0] = (bf16)a0; o[1] = (bf16)a1; o[2] = (bf16)a2; o[3] = (bf16)a3;
        *(bf16x4v*)&Sarr[(size_t)node * 256 + c] = o;
        if (lane == 0) deg[(rev ? NP : 0) + node] = kc2;
    }
}

// ---------------- fused node MLP: Hid in LDS, out = Hid@Wt2^T + bn2 + NS ----------------
__global__ __launch_bounds__(256) void k_node(
    const bf16* __restrict__ S_to, const bf16* __restrict__ S_fr,
    const float* __restrict__ NS, const bf16* __restrict__ Wth,
    const bf16* __restrict__ Wt2,
    const float* __restrict__ u, const float* __restrict__ ru,
    const float* __restrict__ bn1, const float* __restrict__ bn2,
    const int* __restrict__ deg, float* __restrict__ out, int NP, int N) {
    __shared__ __align__(16) unsigned char smem[51200];   // As(10240)+Bs(40960); Hs aliases
    bf16 (*As)[64][40]  = (bf16(*)[64][40])smem;          // [2][64][40]
    bf16 (*Bs)[256][40] = (bf16(*)[256][40])(smem + 10240); // [2][256][40]
    bf16 (*Hs)[264] = (bf16(*)[264])smem;                 // [64][264]
    const int tid = threadIdx.x;
    const int wv = tid >> 6, lane = tid & 63;
    const int l15 = lane & 15, quad = lane >> 4;
    const int row0 = blockIdx.x * 64;
    const int srow4 = tid >> 2, kc = (tid & 3) * 8;
    floatx4 acc[4][4] = {};   // [colstrip][rowtile]; wave covers cols wv*64..+64
    const int arow = row0 + srow4;
    auto loadA = [&](int k) -> bf16x8 {
        if (k < 512) {
            const bf16* S = (k < 256) ? S_to : S_fr;
            return *(const bf16x8*)&S[(size_t)arow * 256 + (k & 255) + kc];
        }
        return ns8(NS, arow, (k - 512) + kc, N);
    };
    for (int k0 = 0; k0 < 640; k0 += 64) {
        bf16x8 av0 = loadA(k0);
        bf16x8 av1 = loadA(k0 + 32);
        bf16x8 bv[2][4];
#pragma unroll
        for (int h = 0; h < 2; ++h)
#pragma unroll
            for (int j = 0; j < 4; ++j)
                bv[h][j] = *(const bf16x8*)&Wth[(size_t)(srow4 + 64 * j) * 640 + k0 + h * 32 + kc];
        __syncthreads();
        *(bf16x8*)&As[0][srow4][kc] = av0;
        *(bf16x8*)&As[1][srow4][kc] = av1;
#pragma unroll
        for (int h = 0; h < 2; ++h)
#pragma unroll
            for (int j = 0; j < 4; ++j)
                *(bf16x8*)&Bs[h][srow4 + 64 * j][kc] = bv[h][j];
        __syncthreads();
#pragma unroll
        for (int h = 0; h < 2; ++h)
#pragma unroll
            for (int s = 0; s < 4; ++s) {
                bf16x8 bfr = *(const bf16x8*)&Bs[h][wv * 64 + s * 16 + l15][quad * 8];
#pragma unroll
                for (int r = 0; r < 4; ++r) {
                    bf16x8 afr = *(const bf16x8*)&As[h][r * 16 + l15][quad * 8];
                    acc[s][r] = __builtin_amdgcn_mfma_f32_16x16x32_bf16(afr, bfr, acc[s][r], 0, 0, 0);
                }
            }
    }
    __syncthreads();   // all As/Bs reads done before Hs overwrite
    // epilogue 1: deg terms + bias + relu -> Hs
#pragma unroll
    for (int s = 0; s < 4; ++s) {
        int col = wv * 64 + s * 16 + l15;
        float uc = u[col], rc = ru[col], bc = bn1[col];
#pragma unroll
        for (int r = 0; r < 4; ++r)
#pragma unroll
            for (int i = 0; i < 4; ++i) {
                int row = r * 16 + quad * 4 + i;
                float v = acc[s][r][i] + (float)deg[row0 + row] * uc
                        + (float)deg[NP + row0 + row] * rc + bc;
                Hs[row][col] = (bf16)fmaxf(v, 0.f);
            }
    }
    __syncthreads();
    // phase 2: out[64x128]; wave covers cols wv*32..+32 (2 strips)
    floatx4 acc2[2][4] = {};
    for (int k0 = 0; k0 < HH; k0 += 32) {
        bf16x8 afr[4];
#pragma unroll
        for (int r = 0; r < 4; ++r)
            afr[r] = *(const bf16x8*)&Hs[r * 16 + l15][k0 + quad * 8];
#pragma unroll
        for (int s = 0; s < 2; ++s) {
            int col = wv * 32 + s * 16 + l15;
            bf16x8 bfr = *(const bf16x8*)&Wt2[(size_t)col * HH + k0 + quad * 8];
#pragma unroll
            for (int r = 0; r < 4; ++r)
                acc2[s][r] = __builtin_amdgcn_mfma_f32_16x16x32_bf16(afr[r], bfr, acc2[s][r], 0, 0, 0);
        }
    }
#pragma unroll
    for (int s = 0; s < 2; ++s) {
        int ocol = wv * 32 + s * 16 + l15;
        float bb = bn2[ocol];
#pragma unroll
        for (int r = 0; r < 4; ++r)
#pragma unroll
            for (int i = 0; i < 4; ++i) {
                int orow = row0 + r * 16 + quad * 4 + i;
                if (orow < N)
                    out[(size_t)orow * DD + ocol] = acc2[s][r][i] + bb + NS[(size_t)orow * DD + ocol];
            }
    }
}

extern "C" void kernel_launch(void* const* d_in, const int* in_sizes, int n_in,
                              void* d_out, int out_size, void* d_ws, size_t ws_size,
                              hipStream_t stream) {
    const float* NS   = (const float*)d_in[0];
    const float* ef   = (const float*)d_in[1];
    const int* from_idx = (const int*)d_in[2];
    const int* to_idx   = (const int*)d_in[3];
    const float* W1  = (const float*)d_in[4];
    const float* b1  = (const float*)d_in[5];
    const float* W2  = (const float*)d_in[6];
    const float* b2  = (const float*)d_in[7];
    const float* RW1 = (const float*)d_in[8];
    const float* Rb1 = (const float*)d_in[9];
    const float* RW2 = (const float*)d_in[10];
    const float* Rb2 = (const float*)d_in[11];
    const float* Wn1 = (const float*)d_in[12];
    const float* bn1 = (const float*)d_in[13];
    const float* Wn2 = (const float*)d_in[14];
    const float* bn2 = (const float*)d_in[15];

    const int N  = in_sizes[0] / DD;
    const int E  = in_sizes[2];
    const int NP = ((N + 63) / 64) * 64;
    const int MB = NP / 64;
    const int NBF = NP / 32;
    const int NBINS = 2 * NBF;
    const int BINB = (E + 2047) / 2048;
    const int FRONT = BINB + 769 + 16 * MB;
    const int PREB = 512 + (NBINS + 255) / 256;

    char* base = (char*)d_ws;
    size_t off_b = 0;
    auto alloc = [&](size_t b) { size_t o = off_b; off_b += (b + 255) & ~(size_t)255; return o; };
    unsigned char* Pn = (unsigned char*)(base + alloc((size_t)NP * 512));
    bf16* Pf   = (bf16*)(base + alloc((size_t)NP * 512 * 2));
    bf16* S_to = (bf16*)(base + alloc((size_t)NP * 256 * 2));
    bf16* S_fr = (bf16*)(base + alloc((size_t)NP * 256 * 2));
    int* deg   = (int*)(base + alloc((size_t)2 * NP * 4));
    int* gcur  = (int*)(base + alloc((size_t)NBINS * 4));
    int2* binbuf = (int2*)(base + alloc((size_t)NBINS * CAPB * 8));
    bf16* Wt1 = (bf16*)(base + alloc(1024 * 128 * 2));
    bf16* Wth = (bf16*)(base + alloc(256 * 640 * 2));
    bf16* Wt2 = (bf16*)(base + alloc(128 * 256 * 2));
    float* u  = (float*)(base + alloc(256 * 4));
    float* ru = (float*)(base + alloc(256 * 4));

    k_pre<<<PREB, 256, 0, stream>>>(W1, RW1, Wt1, gcur, NBINS);
    k_front<<<FRONT, 256, 0, stream>>>(NS, from_idx, to_idx, ef,
                                       W2, RW2, Wn1, Wn2, b2, Rb2, Wt1,
                                       gcur, binbuf, Pn, Pf, Wth, Wt2, u, ru,
                                       E, N, NP, NBINS, BINB, MB);
    k_aggf<<<NBINS, 256, 0, stream>>>(Pn, Pf, binbuf, gcur, W1, b1, RW1, Rb1,
                                      S_to, S_fr, deg, NP);
    k_node<<<MB, 256, 0, stream>>>(S_to, S_fr, NS, Wth, Wt2, u, ru, bn1, bn2,
                                   deg, (float*)d_out, NP, N);
}

// Round 10
// 320.679 us; speedup vs baseline: 1.0794x; 1.0272x over previous
//
#include <hip/hip_runtime.h>
#include <hip/hip_bf16.h>

// GraphPropLayer on MI355X — round 10: proj does 2 col-tiles/block (A reuse),
// k_node reverted to BK=32 (33.8 KB LDS, 4 blocks/CU).
// 4 dispatches:
//  (1) k_pre: Wt1 transpose prep + gcur zeroing.
//  (2) k_front: [bins | Wth/Wt2/u/ru prep | proj GEMM] in one grid.
//  (3) k_aggf: one block per 32-node bin: LDS counting-sort, register
//      relu-accumulate, 8-deep fp8 gathers -> S_to/S_fr + deg.
//  (4) k_node: Hid = relu([S|S|NS]@Wth^T + deg*u + bn1) in regs -> LDS;
//      out = Hid @ Wt2^T + bn2 + NS. Hid never hits global.

typedef __bf16 bf16;
typedef __attribute__((ext_vector_type(8))) __bf16 bf16x8;
typedef __attribute__((ext_vector_type(4))) __bf16 bf16x4v;
typedef __attribute__((ext_vector_type(4))) float floatx4;
typedef __attribute__((ext_vector_type(2))) float floatx2;

#define DD 128
#define HH 256
#define CAPB 800       // records per 32-node bin; mean 512, sigma 23 -> 12 sigma
#define MAXBINS 3200   // >= 2*NP/32 for N <= 51200

__device__ __forceinline__ bf16x8 ns8(const float* __restrict__ NS, int row, int col, int N) {
    bf16x8 v;
    if (row < N) {
        float4 f0 = *(const float4*)&NS[(size_t)row * DD + col];
        float4 f1 = *(const float4*)&NS[(size_t)row * DD + col + 4];
        v[0] = (bf16)f0.x; v[1] = (bf16)f0.y; v[2] = (bf16)f0.z; v[3] = (bf16)f0.w;
        v[4] = (bf16)f1.x; v[5] = (bf16)f1.y; v[6] = (bf16)f1.z; v[7] = (bf16)f1.w;
    } else {
        v = (bf16x8)(bf16)0.0f;
    }
    return v;
}

// ---------------- pre: Wt1 transpose + gcur zero ----------------
__global__ void k_pre(const float* __restrict__ W1, const float* __restrict__ RW1,
                      bf16* __restrict__ Wt1, int* __restrict__ gcur, int NBINS) {
    const int b = blockIdx.x, t = threadIdx.x;
    if (b < 512) {                       // Wt1[n][k]: transposed W1/RW1 blocks
        int idx = b * 256 + t;
        int n = idx >> 7, k = idx & 127;
        float v;
        if (n < 256)      v = W1[k * 256 + n];
        else if (n < 512) v = W1[(128 + k) * 256 + (n - 256)];
        else if (n < 768) v = RW1[k * 256 + (n - 512)];
        else              v = RW1[(128 + k) * 256 + (n - 768)];
        Wt1[idx] = (bf16)v;
    } else {
        int i = (b - 512) * 256 + t;
        if (i < NBINS) gcur[i] = 0;
    }
}

// ---------------- fused front: bins | prep | proj ----------------
__global__ __launch_bounds__(256) void k_front(
    const float* __restrict__ NS, const int* __restrict__ from_idx,
    const int* __restrict__ to_idx, const float* __restrict__ ef,
    const float* __restrict__ W2, const float* __restrict__ RW2,
    const float* __restrict__ Wn1, const float* __restrict__ Wn2,
    const float* __restrict__ b2, const float* __restrict__ Rb2,
    const bf16* __restrict__ Wt1,
    int* __restrict__ gcur, int2* __restrict__ binbuf,
    unsigned char* __restrict__ Pn, bf16* __restrict__ Pf,
    bf16* __restrict__ Wth, bf16* __restrict__ Wt2,
    float* __restrict__ u, float* __restrict__ ru,
    int E, int N, int NP, int NBINS, int BINB, int MB) {
    __shared__ __align__(16) unsigned char smem[30720];
    const int b = blockIdx.x, t = threadIdx.x;

    if (b < BINB) {
        // ---------- edge binning: 2048 edges/block, 32-node bins ----------
        int* hist = (int*)smem;
        int* base = hist + MAXBINS;
        const int NBF = NP >> 5;
        for (int i = t; i < NBINS; i += 256) hist[i] = 0;
        __syncthreads();
        const int e0 = b * 2048;
        int f[8], tt[8]; float w[8]; bool valid[8];
#pragma unroll
        for (int q = 0; q < 8; ++q) {
            int e = e0 + q * 256 + t;
            valid[q] = e < E;
            int ec = valid[q] ? e : 0;
            f[q] = from_idx[ec]; tt[q] = to_idx[ec]; w[q] = ef[ec];
        }
#pragma unroll
        for (int q = 0; q < 8; ++q) {
            if (valid[q]) {
                atomicAdd(&hist[tt[q] >> 5], 1);
                atomicAdd(&hist[NBF + (f[q] >> 5)], 1);
            }
        }
        __syncthreads();
        for (int i = t; i < NBINS; i += 256) {
            int h = hist[i];
            base[i] = h ? atomicAdd(&gcur[i], h) : 0;
            hist[i] = 0;
        }
        __syncthreads();
#pragma unroll
        for (int q = 0; q < 8; ++q) {
            if (valid[q]) {
                int wb = __float_as_int(w[q]);
                int b1 = tt[q] >> 5;
                int r1 = base[b1] + atomicAdd(&hist[b1], 1);
                if (r1 < CAPB)
                    binbuf[(size_t)b1 * CAPB + r1] = make_int2(((tt[q] & 31) << 17) | f[q], wb);
                int b2i = NBF + (f[q] >> 5);
                int r2 = base[b2i] + atomicAdd(&hist[b2i], 1);
                if (r2 < CAPB)
                    binbuf[(size_t)b2i * CAPB + r2] = make_int2(((f[q] & 31) << 17) | tt[q], wb);
            }
        }
        return;
    }

    if (b < BINB + 769) {
        // ---------- weight prep (consumed only by k_node) ----------
        int bb = b - BINB;
        if (bb < 640) {                  // Wth[m][k]: W2@Wn1_top | RW2@Wn1_top | Wn1_bot
            int k = bb, m = t;
            float v;
            if (k < 512) {
                const float* Wsrc = (k < 256) ? W2 : RW2;
                int i = k & 255;
                float acc = 0.f;
                for (int j = 0; j < 256; ++j) acc += Wsrc[i * 256 + j] * Wn1[j * 256 + m];
                v = acc;
            } else {
                v = Wn1[(256 + k - 512) * 256 + m];
            }
            Wth[m * 640 + k] = (bf16)v;
        } else if (bb < 768) {           // Wt2[n][k] = Wn2^T
            int idx = (bb - 640) * 256 + t;
            int n = idx >> 8, k = idx & 255;
            Wt2[idx] = (bf16)Wn2[k * 128 + n];
        } else {                         // u = b2@Wn1_top, ru = Rb2@Wn1_top
            int m = t;
            float a = 0.f, c2 = 0.f;
            for (int j = 0; j < 256; ++j) {
                float w = Wn1[j * 256 + m];
                a += b2[j] * w;
                c2 += Rb2[j] * w;
            }
            u[m] = a;
            ru[m] = c2;
        }
        return;
    }

    // ---------- projection GEMM: 2 col-tiles per block, A reused ----------
    {
        bf16 (*As)[64][40] = (bf16(*)[64][40])smem;                 // [2][64][40]
        bf16 (*Bs)[2][64][40] = (bf16(*)[2][64][40])(smem + 10240); // [cp][h][64][40]
        const int p = b - (BINB + 769);
        const int row0 = (p >> 3) * 64;           // 8 consecutive blocks share NS rows
        const int colp = (p & 7) * 128;           // two 64-col tiles: colp, colp+64
        const int wv = t >> 6, lane = t & 63;
        const int l15 = lane & 15, quad = lane >> 4;
        const int srow = t >> 2, kc = (t & 3) * 8;
        floatx4 acc[2][4] = {};
        for (int k0 = 0; k0 < DD; k0 += 64) {
            bf16x8 av0 = ns8(NS, row0 + srow, k0 + kc, N);
            bf16x8 av1 = ns8(NS, row0 + srow, k0 + 32 + kc, N);
            bf16x8 bv00 = *(const bf16x8*)&Wt1[(size_t)(colp + srow) * DD + k0 + kc];
            bf16x8 bv01 = *(const bf16x8*)&Wt1[(size_t)(colp + srow) * DD + k0 + 32 + kc];
            bf16x8 bv10 = *(const bf16x8*)&Wt1[(size_t)(colp + 64 + srow) * DD + k0 + kc];
            bf16x8 bv11 = *(const bf16x8*)&Wt1[(size_t)(colp + 64 + srow) * DD + k0 + 32 + kc];
            __syncthreads();
            *(bf16x8*)&As[0][srow][kc] = av0;
            *(bf16x8*)&As[1][srow][kc] = av1;
            *(bf16x8*)&Bs[0][0][srow][kc] = bv00;
            *(bf16x8*)&Bs[0][1][srow][kc] = bv01;
            *(bf16x8*)&Bs[1][0][srow][kc] = bv10;
            *(bf16x8*)&Bs[1][1][srow][kc] = bv11;
            __syncthreads();
#pragma unroll
            for (int h = 0; h < 2; ++h) {
                bf16x8 afr[4];
#pragma unroll
                for (int r = 0; r < 4; ++r)
                    afr[r] = *(const bf16x8*)&As[h][r * 16 + l15][quad * 8];
#pragma unroll
                for (int cp = 0; cp < 2; ++cp) {
                    bf16x8 bfr = *(const bf16x8*)&Bs[cp][h][wv * 16 + l15][quad * 8];
#pragma unroll
                    for (int r = 0; r < 4; ++r)
                        acc[cp][r] = __builtin_amdgcn_mfma_f32_16x16x32_bf16(afr[r], bfr, acc[cp][r], 0, 0, 0);
                }
            }
        }
#pragma unroll
        for (int cp = 0; cp < 2; ++cp) {
            const int ocol = colp + cp * 64 + wv * 16 + l15;  // [0,1024)
            const int ch = ocol & 255;
            const int half = (ocol >> 9) & 1;                 // 0=fwd pair, 1=rev pair
            const bool isNbr = ((ocol >> 8) & 1) == 0;        // fp8 nbr halves
#pragma unroll
            for (int r = 0; r < 4; ++r)
#pragma unroll
                for (int i = 0; i < 4; ++i) {
                    int orow = row0 + r * 16 + quad * 4 + i;
                    float v = acc[cp][r][i];
                    if (isNbr) {
                        int pk = __builtin_amdgcn_cvt_pk_fp8_f32(v, v, 0, false);
                        Pn[(size_t)orow * 512 + half * 256 + ch] = (unsigned char)(pk & 0xFF);
                    } else {
                        Pf[(size_t)orow * 512 + half * 256 + ch] = (bf16)v;
                    }
                }
        }
    }
}

// ---------------- aggregation: one block per 32-node bin, 8-deep gathers ----------------
__global__ __launch_bounds__(256) void k_aggf(
    const unsigned char* __restrict__ Pn, const bf16* __restrict__ Pf,
    const int2* __restrict__ binbuf, const int* __restrict__ gcnt,
    const float* __restrict__ W1, const float* __restrict__ b1,
    const float* __restrict__ RW1, const float* __restrict__ Rb1,
    bf16* __restrict__ S_to, bf16* __restrict__ S_fr,
    int* __restrict__ deg, int NP) {
    __shared__ int hist[32], kstart[32], cur[32], scanbuf[32];
    __shared__ int2 srec[CAPB];
    const int b = blockIdx.x, t = threadIdx.x;
    const int NBF = NP >> 5;
    const bool rev = b >= NBF;
    const int node0 = (rev ? b - NBF : b) << 5;
    int cnt = gcnt[b]; if (cnt > CAPB) cnt = CAPB;
    const int2* bin = binbuf + (size_t)b * CAPB;
    if (t < 32) hist[t] = 0;
    __syncthreads();
    for (int i = t; i < cnt; i += 256)
        atomicAdd(&hist[((unsigned)bin[i].x) >> 17], 1);
    __syncthreads();
    if (t < 32) scanbuf[t] = hist[t];
    __syncthreads();
    for (int d = 1; d < 32; d <<= 1) {
        int v = (t < 32 && t >= d) ? scanbuf[t - d] : 0;
        __syncthreads();
        if (t < 32) scanbuf[t] += v;
        __syncthreads();
    }
    if (t < 32) { kstart[t] = scanbuf[t] - hist[t]; cur[t] = scanbuf[t] - hist[t]; }
    __syncthreads();
    for (int i = t; i < cnt; i += 256) {
        int2 r = bin[i];
        int rk = atomicAdd(&cur[((unsigned)r.x) >> 17], 1);
        srec[rk] = r;
    }
    __syncthreads();
    const int wv = t >> 6, lane = t & 63, c = lane * 4;
    const int fixoff = rev ? 256 : 0;     // into Pf row (elements)
    const int nbroff = rev ? 256 : 0;     // into Pn row (bytes)
    const float* bb = rev ? Rb1 : b1;
    const float* wl = (rev ? RW1 : W1) + 65536;   // row 256 of [257,256]
    float4 bv = *(const float4*)&bb[c];
    float4 wv4 = *(const float4*)&wl[c];
    bf16* Sarr = rev ? S_fr : S_to;
    for (int key = wv; key < 32; key += 4) {
        int node = node0 + key;
        bf16x4v pf = *(const bf16x4v*)&Pf[(size_t)node * 512 + fixoff + c];
        float fx0 = (float)pf[0] + bv.x;
        float fx1 = (float)pf[1] + bv.y;
        float fx2 = (float)pf[2] + bv.z;
        float fx3 = (float)pf[3] + bv.w;
        int beg = kstart[key], kc2 = hist[key], end = beg + kc2;
        float a0 = 0.f, a1 = 0.f, a2 = 0.f, a3 = 0.f;
        int j = beg;
        for (; j + 8 <= end; j += 8) {
            int2 rr[8]; int qq[8];
#pragma unroll
            for (int z = 0; z < 8; ++z) rr[z] = srec[j + z];
#pragma unroll
            for (int z = 0; z < 8; ++z)
                qq[z] = *(const int*)&Pn[(size_t)(rr[z].x & 0x1FFFF) * 512 + nbroff + c];
#pragma unroll
            for (int z = 0; z < 8; ++z) {
                float w = __int_as_float(rr[z].y);
                floatx2 lo = __builtin_amdgcn_cvt_pk_f32_fp8(qq[z], false);
                floatx2 hi = __builtin_amdgcn_cvt_pk_f32_fp8(qq[z], true);
                a0 += fmaxf(fx0 + lo.x + w * wv4.x, 0.f);
                a1 += fmaxf(fx1 + lo.y + w * wv4.y, 0.f);
                a2 += fmaxf(fx2 + hi.x + w * wv4.z, 0.f);
                a3 += fmaxf(fx3 + hi.y + w * wv4.w, 0.f);
            }
        }
        for (; j < end; ++j) {
            int2 r = srec[j];
            int qq = *(const int*)&Pn[(size_t)(r.x & 0x1FFFF) * 512 + nbroff + c];
            float w = __int_as_float(r.y);
            floatx2 lo = __builtin_amdgcn_cvt_pk_f32_fp8(qq, false);
            floatx2 hi = __builtin_amdgcn_cvt_pk_f32_fp8(qq, true);
            a0 += fmaxf(fx0 + lo.x + w * wv4.x, 0.f);
            a1 += fmaxf(fx1 + lo.y + w * wv4.y, 0.f);
            a2 += fmaxf(fx2 + hi.x + w * wv4.z, 0.f);
            a3 += fmaxf(fx3 + hi.y + w * wv4.w, 0.f);
        }
        bf16x4v o;
        o[0] = (bf16)a0; o[1] = (bf16)a1; o[2] = (bf16)a2; o[3] = (bf16)a3;
        *(bf16x4v*)&Sarr[(size_t)node * 256 + c] = o;
        if (lane == 0) deg[(rev ? NP : 0) + node] = kc2;
    }
}

// ---------------- fused node MLP (BK=32): Hid in LDS, out = Hid@Wt2^T + bn2 + NS ----------------
__global__ __launch_bounds__(256) void k_node(
    const bf16* __restrict__ S_to, const bf16* __restrict__ S_fr,
    const float* __restrict__ NS, const bf16* __restrict__ Wth,
    const bf16* __restrict__ Wt2,
    const float* __restrict__ u, const float* __restrict__ ru,
    const float* __restrict__ bn1, const float* __restrict__ bn2,
    const int* __restrict__ deg, float* __restrict__ out, int NP, int N) {
    __shared__ __align__(16) unsigned char smem[33792];   // max(As+Bs=25600, Hs=33792)
    bf16 (*As)[40]  = (bf16(*)[40])smem;                  // [64][40]
    bf16 (*Bs)[40]  = (bf16(*)[40])(smem + 5120);         // [256][40]
    bf16 (*Hs)[264] = (bf16(*)[264])smem;                 // [64][264]
    const int tid = threadIdx.x;
    const int wv = tid >> 6, lane = tid & 63;
    const int l15 = lane & 15, quad = lane >> 4;
    const int row0 = blockIdx.x * 64;
    const int srow = tid >> 2, kc = (tid & 3) * 8;
    floatx4 acc[4][4] = {};   // [colstrip][rowtile]; wave covers cols wv*64..+64
    const int arow = row0 + srow;
    for (int k0 = 0; k0 < 640; k0 += 32) {
        bf16x8 av;
        if (k0 < 512) {
            const bf16* S = (k0 < 256) ? S_to : S_fr;
            av = *(const bf16x8*)&S[(size_t)arow * 256 + (k0 & 255) + kc];
        } else {
            av = ns8(NS, arow, (k0 - 512) + kc, N);
        }
        bf16x8 bv[4];
#pragma unroll
        for (int j = 0; j < 4; ++j)
            bv[j] = *(const bf16x8*)&Wth[(size_t)(srow + 64 * j) * 640 + k0 + kc];
        __syncthreads();
        *(bf16x8*)&As[srow][kc] = av;
#pragma unroll
        for (int j = 0; j < 4; ++j)
            *(bf16x8*)&Bs[srow + 64 * j][kc] = bv[j];
        __syncthreads();
#pragma unroll
        for (int s = 0; s < 4; ++s) {
            bf16x8 bfr = *(const bf16x8*)&Bs[wv * 64 + s * 16 + l15][quad * 8];
#pragma unroll
            for (int r = 0; r < 4; ++r) {
                bf16x8 afr = *(const bf16x8*)&As[r * 16 + l15][quad * 8];
                acc[s][r] = __builtin_amdgcn_mfma_f32_16x16x32_bf16(afr, bfr, acc[s][r], 0, 0, 0);
            }
        }
    }
    __syncthreads();   // all As/Bs reads done before Hs overwrite
    // epilogue 1: deg terms + bias + relu -> Hs
#pragma unroll
    for (int s = 0; s < 4; ++s) {
        int col = wv * 64 + s * 16 + l15;
        float uc = u[col], rc = ru[col], bc = bn1[col];
#pragma unroll
        for (int r = 0; r < 4; ++r)
#pragma unroll
            for (int i = 0; i < 4; ++i) {
                int row = r * 16 + quad * 4 + i;
                float v = acc[s][r][i] + (float)deg[row0 + row] * uc
                        + (float)deg[NP + row0 + row] * rc + bc;
                Hs[row][col] = (bf16)fmaxf(v, 0.f);
            }
    }
    __syncthreads();
    // phase 2: out[64x128]; wave covers cols wv*32..+32 (2 strips)
    floatx4 acc2[2][4] = {};
    for (int k0 = 0; k0 < HH; k0 += 32) {
        bf16x8 afr[4];
#pragma unroll
        for (int r = 0; r < 4; ++r)
            afr[r] = *(const bf16x8*)&Hs[r * 16 + l15][k0 + quad * 8];
#pragma unroll
        for (int s = 0; s < 2; ++s) {
            int col = wv * 32 + s * 16 + l15;
            bf16x8 bfr = *(const bf16x8*)&Wt2[(size_t)col * HH + k0 + quad * 8];
#pragma unroll
            for (int r = 0; r < 4; ++r)
                acc2[s][r] = __builtin_amdgcn_mfma_f32_16x16x32_bf16(afr[r], bfr, acc2[s][r], 0, 0, 0);
        }
    }
#pragma unroll
    for (int s = 0; s < 2; ++s) {
        int ocol = wv * 32 + s * 16 + l15;
        float bb = bn2[ocol];
#pragma unroll
        for (int r = 0; r < 4; ++r)
#pragma unroll
            for (int i = 0; i < 4; ++i) {
                int orow = row0 + r * 16 + quad * 4 + i;
                if (orow < N)
                    out[(size_t)orow * DD + ocol] = acc2[s][r][i] + bb + NS[(size_t)orow * DD + ocol];
            }
    }
}

extern "C" void kernel_launch(void* const* d_in, const int* in_sizes, int n_in,
                              void* d_out, int out_size, void* d_ws, size_t ws_size,
                              hipStream_t stream) {
    const float* NS   = (const float*)d_in[0];
    const float* ef   = (const float*)d_in[1];
    const int* from_idx = (const int*)d_in[2];
    const int* to_idx   = (const int*)d_in[3];
    const float* W1  = (const float*)d_in[4];
    const float* b1  = (const float*)d_in[5];
    const float* W2  = (const float*)d_in[6];
    const float* b2  = (const float*)d_in[7];
    const float* RW1 = (const float*)d_in[8];
    const float* Rb1 = (const float*)d_in[9];
    const float* RW2 = (const float*)d_in[10];
    const float* Rb2 = (const float*)d_in[11];
    const float* Wn1 = (const float*)d_in[12];
    const float* bn1 = (const float*)d_in[13];
    const float* Wn2 = (const float*)d_in[14];
    const float* bn2 = (const float*)d_in[15];

    const int N  = in_sizes[0] / DD;
    const int E  = in_sizes[2];
    const int NP = ((N + 63) / 64) * 64;
    const int MB = NP / 64;
    const int NBF = NP / 32;
    const int NBINS = 2 * NBF;
    const int BINB = (E + 2047) / 2048;
    const int FRONT = BINB + 769 + 8 * MB;
    const int PREB = 512 + (NBINS + 255) / 256;

    char* base = (char*)d_ws;
    size_t off_b = 0;
    auto alloc = [&](size_t b) { size_t o = off_b; off_b += (b + 255) & ~(size_t)255; return o; };
    unsigned char* Pn = (unsigned char*)(base + alloc((size_t)NP * 512));
    bf16* Pf   = (bf16*)(base + alloc((size_t)NP * 512 * 2));
    bf16* S_to = (bf16*)(base + alloc((size_t)NP * 256 * 2));
    bf16* S_fr = (bf16*)(base + alloc((size_t)NP * 256 * 2));
    int* deg   = (int*)(base + alloc((size_t)2 * NP * 4));
    int* gcur  = (int*)(base + alloc((size_t)NBINS * 4));
    int2* binbuf = (int2*)(base + alloc((size_t)NBINS * CAPB * 8));
    bf16* Wt1 = (bf16*)(base + alloc(1024 * 128 * 2));
    bf16* Wth = (bf16*)(base + alloc(256 * 640 * 2));
    bf16* Wt2 = (bf16*)(base + alloc(128 * 256 * 2));
    float* u  = (float*)(base + alloc(256 * 4));
    float* ru = (float*)(base + alloc(256 * 4));

    k_pre<<<PREB, 256, 0, stream>>>(W1, RW1, Wt1, gcur, NBINS);
    k_front<<<FRONT, 256, 0, stream>>>(NS, from_idx, to_idx, ef,
                                       W2, RW2, Wn1, Wn2, b2, Rb2, Wt1,
                                       gcur, binbuf, Pn, Pf, Wth, Wt2, u, ru,
                                       E, N, NP, NBINS, BINB, MB);
    k_aggf<<<NBINS, 256, 0, stream>>>(Pn, Pf, binbuf, gcur, W1, b1, RW1, Rb1,
                                      S_to, S_fr, deg, NP);
    k_node<<<MB, 256, 0, stream>>>(S_to, S_fr, NS, Wth, Wt2, u, ru, bn1, bn2,
                                   deg, (float*)d_out, NP, N);
}